// Round 13
// baseline (199.619 us; speedup 1.0000x reference)
//
#include <hip/hip_runtime.h>
#include <hip/hip_bf16.h>

#define D 128
#define CAP 56  // padded CSR capacity; deg~Poisson(16), P(deg>56) ~ 1e-15/node
#define SC 8    // stats partial copies (contention /8)
#define CS 16   // cnt stride (ints): one counter per 64B line (measured-neutral, kept)
#define NCONVB 640  // convert-specialized blocks (of 2500): convert hides under scatter

typedef unsigned int uint32;
typedef __attribute__((ext_vector_type(8))) short bf16x8;   // 8 bf16 (4 VGPRs)
typedef __attribute__((ext_vector_type(4))) float f32x4;    // MFMA accumulator

__device__ __forceinline__ float bflo(uint32 u) { return __uint_as_float(u << 16); }
__device__ __forceinline__ float bfhi(uint32 u) { return __uint_as_float(u & 0xffff0000u); }
__device__ __forceinline__ unsigned short f2bf(float f) {   // RNE fp32->bf16
    uint32 u = __float_as_uint(f);
    return (unsigned short)((u + 0x7FFFu + ((u >> 16) & 1u)) >> 16);
}

// ---------------------------------------------------------------------------
// scatter+convert, BLOCK-SPECIALIZED (R12): scatter is coherence-point-bound
// (VALUBusy 2%, BW 18% — R11 measured), so giving 640 of 2500 blocks to the
// ~31MB conversion runs it concurrently on other CUs, hiding its ~5.5us
// under the scatter's ~38us instead of serializing it (R10's thread-serial
// interleave was null because every thread did edge-then-convert in phase).
// ---------------------------------------------------------------------------
__global__ __launch_bounds__(256) void scatterconv_kernel(
    const int* __restrict__ src, const int* __restrict__ dst,
    int* __restrict__ cnt, int* __restrict__ esrc,
    const float4* __restrict__ x4, uint2* __restrict__ xh2,
    const float4* __restrict__ W4, uint2* __restrict__ W16,
    float* __restrict__ statp, int E, int N)
{
    const int tid = threadIdx.x;
    const int nb  = gridDim.x;
    const int nsb = nb - NCONVB;            // scatter blocks: [0, nsb)

    if ((int)blockIdx.x < nsb) {
        // ---- scatter specialization ----
        const int gtid  = blockIdx.x * 256 + tid;
        const int gsize = nsb * 256;
        const uint32 sent = (uint32)cnt[(long)N * CS];   // poisoned-uniform

        if (gtid < SC * 256) statp[gtid] = 0.0f;

        for (int e = gtid; e < E; e += gsize) {
            int d = dst[e];
            int s = src[e];                           // issues with dst
            if ((unsigned)d < (unsigned)N) {
                uint32 old = (uint32)atomicAdd(&cnt[(long)d * CS], 1);
                uint32 p = old - sent;                    // 0-based slot
                if (p < (uint32)CAP) {
                    esrc[(long)d * CAP + p] = min(max(s, 0), N - 1);
                }
            }
        }
    } else {
        // ---- convert specialization: x (20.5MB) + W -> bf16 ----
        const int gtid  = (blockIdx.x - nsb) * 256 + tid;
        const int gsize = NCONVB * 256;

        const long total = (long)N * 32;   // float4 slots
        for (long idx = gtid; idx < total; idx += gsize) {
            float4 v = x4[idx];
            uint2 o;
            o.x = (uint32)f2bf(v.x) | ((uint32)f2bf(v.y) << 16);
            o.y = (uint32)f2bf(v.z) | ((uint32)f2bf(v.w) << 16);
            xh2[idx] = o;
        }
        for (int idx = gtid; idx < (D * D) / 4; idx += gsize) {   // 4096 groups
            float4 v = W4[idx];
            uint2 o;
            o.x = (uint32)f2bf(v.x) | ((uint32)f2bf(v.y) << 16);
            o.y = (uint32)f2bf(v.z) | ((uint32)f2bf(v.w) << 16);
            W16[idx] = o;
        }
    }
}

// ---------------------------------------------------------------------------
// Merged gather + MFMA GEMM + BN stats (R7-proven structure).
// R12 change: __launch_bounds__(256, 8) — request 8 waves/EU (8 blocks/CU;
// VGPR cap 64, currently 56). R11 measured 34% occupancy on a kernel whose
// BW floor is ~15us but dur 46us -> latency-bound; double resident waves.
// NOTE: paste only P##k, never P##k.x — `0.x` lexes as ONE pp-number token.
// ---------------------------------------------------------------------------
#define ROWL(nm, k, jj) \
    uint4 nm; { int j_ = ((k) < deg) ? (jj) : 0; nm = xh4[j_ * 16 + l16]; }

#define BMASK(P, B) \
    if ((B) + 0 >= deg) { (P##0).x = 0u; (P##0).y = 0u; (P##0).z = 0u; (P##0).w = 0u; } \
    if ((B) + 1 >= deg) { (P##1).x = 0u; (P##1).y = 0u; (P##1).z = 0u; (P##1).w = 0u; } \
    if ((B) + 2 >= deg) { (P##2).x = 0u; (P##2).y = 0u; (P##2).z = 0u; (P##2).w = 0u; } \
    if ((B) + 3 >= deg) { (P##3).x = 0u; (P##3).y = 0u; (P##3).z = 0u; (P##3).w = 0u; } \
    if ((B) + 4 >= deg) { (P##4).x = 0u; (P##4).y = 0u; (P##4).z = 0u; (P##4).w = 0u; } \
    if ((B) + 5 >= deg) { (P##5).x = 0u; (P##5).y = 0u; (P##5).z = 0u; (P##5).w = 0u; } \
    if ((B) + 6 >= deg) { (P##6).x = 0u; (P##6).y = 0u; (P##6).z = 0u; (P##6).w = 0u; } \
    if ((B) + 7 >= deg) { (P##7).x = 0u; (P##7).y = 0u; (P##7).z = 0u; (P##7).w = 0u; }

#define ACC8(P) \
    a0 += (bflo((P##0).x)+bflo((P##1).x)) + (bflo((P##2).x)+bflo((P##3).x)) \
        + (bflo((P##4).x)+bflo((P##5).x)) + (bflo((P##6).x)+bflo((P##7).x)); \
    a1 += (bfhi((P##0).x)+bfhi((P##1).x)) + (bfhi((P##2).x)+bfhi((P##3).x)) \
        + (bfhi((P##4).x)+bfhi((P##5).x)) + (bfhi((P##6).x)+bfhi((P##7).x)); \
    a2 += (bflo((P##0).y)+bflo((P##1).y)) + (bflo((P##2).y)+bflo((P##3).y)) \
        + (bflo((P##4).y)+bflo((P##5).y)) + (bflo((P##6).y)+bflo((P##7).y)); \
    a3 += (bfhi((P##0).y)+bfhi((P##1).y)) + (bfhi((P##2).y)+bfhi((P##3).y)) \
        + (bfhi((P##4).y)+bfhi((P##5).y)) + (bfhi((P##6).y)+bfhi((P##7).y)); \
    a4 += (bflo((P##0).z)+bflo((P##1).z)) + (bflo((P##2).z)+bflo((P##3).z)) \
        + (bflo((P##4).z)+bflo((P##5).z)) + (bflo((P##6).z)+bflo((P##7).z)); \
    a5 += (bfhi((P##0).z)+bfhi((P##1).z)) + (bfhi((P##2).z)+bfhi((P##3).z)) \
        + (bfhi((P##4).z)+bfhi((P##5).z)) + (bfhi((P##6).z)+bfhi((P##7).z)); \
    a6 += (bflo((P##0).w)+bflo((P##1).w)) + (bflo((P##2).w)+bflo((P##3).w)) \
        + (bflo((P##4).w)+bflo((P##5).w)) + (bflo((P##6).w)+bflo((P##7).w)); \
    a7 += (bfhi((P##0).w)+bfhi((P##1).w)) + (bfhi((P##2).w)+bfhi((P##3).w)) \
        + (bfhi((P##4).w)+bfhi((P##5).w)) + (bfhi((P##6).w)+bfhi((P##7).w));

__global__ __launch_bounds__(256, 8) void gathergemm_kernel(
    const uint4* __restrict__ xh4,
    const int* __restrict__ cnt, const int* __restrict__ esrc,
    const unsigned short* __restrict__ W16, const float* __restrict__ bb,
    const float* __restrict__ geps, unsigned short* __restrict__ hlin16,
    float* __restrict__ statp, int N)
{
    __shared__ __align__(16) unsigned short hl[16][136];
    __shared__ float bias_s[D];

    const int tid = threadIdx.x;
    if (tid < D) bias_s[tid] = bb[tid];
    const float eps1 = 1.0f + geps[0];
    const uint32 sent = (uint32)cnt[(long)N * CS];
    const int row0 = blockIdx.x * 16;

    // ---- phase 1: gather 16 rows into LDS (one 16-lane group per row) ----
    const int grp = tid >> 4;     // 0..15 -> row
    const int l16 = tid & 15;     // uint4 slot (16B of the 256B bf16 row)
    {
        const int node = row0 + grp;
        float a0=0.f,a1=0.f,a2=0.f,a3=0.f,a4=0.f,a5=0.f,a6=0.f,a7=0.f;
        int deg = 0; long base = 0;
        int4 ja0 = {0,0,0,0}, jb0 = {0,0,0,0}, ja1 = {0,0,0,0}, jb1 = {0,0,0,0},
             ja2 = {0,0,0,0}, jb2 = {0,0,0,0}, ja3 = {0,0,0,0}, jb3 = {0,0,0,0};
        if (node < N) {
            // everything below issues concurrently: cnt, 32 indices, self row
            deg  = min((int)((uint32)cnt[(long)node * CS] - sent), CAP);
            base = (long)node * CAP;
            const int4* jp = (const int4*)(esrc + base);   // 16B-aligned (224B rows)
            ja0 = jp[0]; jb0 = jp[1]; ja1 = jp[2]; jb1 = jp[3];
            ja2 = jp[4]; jb2 = jp[5]; ja3 = jp[6]; jb3 = jp[7];
            uint4 sx = xh4[(long)node * 16 + l16];         // self row (bf16)
            a0 = bflo(sx.x) * eps1; a1 = bfhi(sx.x) * eps1;
            a2 = bflo(sx.y) * eps1; a3 = bfhi(sx.y) * eps1;
            a4 = bflo(sx.z) * eps1; a5 = bfhi(sx.z) * eps1;
            a6 = bflo(sx.w) * eps1; a7 = bfhi(sx.w) * eps1;
        }
        // B0 + B1 in flight
        ROWL(u00,  0, ja0.x) ROWL(u01,  1, ja0.y) ROWL(u02,  2, ja0.z) ROWL(u03,  3, ja0.w)
        ROWL(u04,  4, jb0.x) ROWL(u05,  5, jb0.y) ROWL(u06,  6, jb0.z) ROWL(u07,  7, jb0.w)
        ROWL(u10,  8, ja1.x) ROWL(u11,  9, ja1.y) ROWL(u12, 10, ja1.z) ROWL(u13, 11, ja1.w)
        ROWL(u14, 12, jb1.x) ROWL(u15, 13, jb1.y) ROWL(u16, 14, jb1.z) ROWL(u17, 15, jb1.w)
        // acc B0 | issue B2
        ROWL(u20, 16, ja2.x) ROWL(u21, 17, ja2.y) ROWL(u22, 18, ja2.z) ROWL(u23, 19, ja2.w)
        ROWL(u24, 20, jb2.x) ROWL(u25, 21, jb2.y) ROWL(u26, 22, jb2.z) ROWL(u27, 23, jb2.w)
        BMASK(u0, 0)
        ACC8(u0)
        // acc B1 | issue B3
        ROWL(u30, 24, ja3.x) ROWL(u31, 25, ja3.y) ROWL(u32, 26, ja3.z) ROWL(u33, 27, ja3.w)
        ROWL(u34, 28, jb3.x) ROWL(u35, 29, jb3.y) ROWL(u36, 30, jb3.z) ROWL(u37, 31, jb3.w)
        BMASK(u1, 8)
        ACC8(u1)
        BMASK(u2, 16)
        ACC8(u2)
        BMASK(u3, 24)
        ACC8(u3)
        // rare tail (P(deg>32) ~ 1e-4)
        for (int e = 32; e < deg; ++e) {
            int j = esrc[base + e];
            uint4 u = xh4[j * 16 + l16];
            a0 += bflo(u.x); a1 += bfhi(u.x);
            a2 += bflo(u.y); a3 += bfhi(u.y);
            a4 += bflo(u.z); a5 += bfhi(u.z);
            a6 += bflo(u.w); a7 += bfhi(u.w);
        }
        uint4 o;
        o.x = (uint32)f2bf(a0) | ((uint32)f2bf(a1) << 16);
        o.y = (uint32)f2bf(a2) | ((uint32)f2bf(a3) << 16);
        o.z = (uint32)f2bf(a4) | ((uint32)f2bf(a5) << 16);
        o.w = (uint32)f2bf(a6) | ((uint32)f2bf(a7) << 16);
        *(uint4*)&hl[grp][l16 * 8] = o;
    }
    __syncthreads();

    // ---- phase 2: MFMA (wave w -> N-tiles 2w, 2w+1) ----
    const int wave = tid >> 6;
    const int l64  = tid & 63;
    const int m    = l64 & 15;
    const int quad = l64 >> 4;

    f32x4 acc0 = (f32x4){0.f, 0.f, 0.f, 0.f};
    f32x4 acc1 = (f32x4){0.f, 0.f, 0.f, 0.f};
    const int n0 = (2 * wave) * 16 + m;
    const int n1 = n0 + 16;
    #pragma unroll
    for (int ks = 0; ks < 4; ++ks) {
        bf16x8 afrag = *(const bf16x8*)&hl[m][ks * 32 + quad * 8];
        bf16x8 b0 = *(const bf16x8*)(W16 + ((long)n0 * D + ks * 32 + quad * 8));
        bf16x8 b1 = *(const bf16x8*)(W16 + ((long)n1 * D + ks * 32 + quad * 8));
        acc0 = __builtin_amdgcn_mfma_f32_16x16x32_bf16(afrag, b0, acc0, 0, 0, 0);
        acc1 = __builtin_amdgcn_mfma_f32_16x16x32_bf16(afrag, b1, acc1, 0, 0, 0);
    }

    // epilogue: bias, bf16 hlin store (stats from fp32), split atomics
    float* sp = statp + (blockIdx.x & (SC - 1)) * 256;
    #pragma unroll
    for (int t = 0; t < 2; ++t) {
        const int col = t ? n1 : n0;              // (2w+t)*16 + m
        const float bias = bias_s[col];
        float ps = 0.f, pq = 0.f;
        #pragma unroll
        for (int r = 0; r < 4; ++r) {
            int gr = row0 + quad * 4 + r;
            float v = (t ? acc1[r] : acc0[r]) + bias;
            if (gr < N) {
                hlin16[(long)gr * D + col] = f2bf(v);
                ps += v;
                pq = fmaf(v, v, pq);
            }
        }
        ps += __shfl_xor(ps, 16); ps += __shfl_xor(ps, 32);
        pq += __shfl_xor(pq, 16); pq += __shfl_xor(pq, 32);
        if (quad == 0) {
            unsafeAtomicAdd(&sp[col],       ps);
            unsafeAtomicAdd(&sp[128 + col], pq);
        }
    }
}

// ---------------------------------------------------------------------------
// Epilogue: sum the SC stats partials -> mean/var -> out = relu(..)+x.
// Reads bf16 h AND bf16 x (both uint32 = 2 cols; same indexing) — residual
// from bf16 x adds <=0.004 abs error (headroom 0.12). Writes fp32 out.
// Grid-stride at 2048 blocks (stats recompute amortized).
// ---------------------------------------------------------------------------
__global__ __launch_bounds__(256) void out_kernel(
    const uint32* __restrict__ h32, const uint32* __restrict__ xh32,
    const float* __restrict__ statp, const float* __restrict__ gamma,
    const float* __restrict__ beta, float invN, float2* __restrict__ dout,
    long total)
{
    __shared__ float ginv[D], sh[D];
    if (threadIdx.x < D) {
        int j = threadIdx.x;
        float s = 0.f, q = 0.f;
        #pragma unroll
        for (int cp = 0; cp < SC; ++cp) {
            s += statp[cp * 256 + j];
            q += statp[cp * 256 + 128 + j];
        }
        float mean = s * invN;
        float var  = q * invN - mean * mean;
        float gv   = gamma[j] * rsqrtf(var + 1e-5f);
        ginv[j] = gv;
        sh[j]   = beta[j] - mean * gv;
    }
    __syncthreads();
    const long stride = (long)gridDim.x * 256;
    for (long t = (long)blockIdx.x * 256 + threadIdx.x; t < total; t += stride) {
        int f = (int)(t & 63);
        uint32 hv = h32[t];
        uint32 xv = xh32[t];
        float v0 = fmaf(bflo(hv), ginv[2 * f],     sh[2 * f]);
        float v1 = fmaf(bfhi(hv), ginv[2 * f + 1], sh[2 * f + 1]);
        v0 = fmaxf(v0, 0.0f) + bflo(xv);
        v1 = fmaxf(v1, 0.0f) + bfhi(xv);
        dout[t] = make_float2(v0, v1);
    }
}

// ---------------------------------------------------------------------------
static inline size_t align16(size_t v) { return (v + 15) & ~(size_t)15; }

extern "C" void kernel_launch(void* const* d_in, const int* in_sizes, int n_in,
                              void* d_out, int out_size, void* d_ws, size_t ws_size,
                              hipStream_t stream)
{
    const float* x     = (const float*)d_in[0];
    const int*   ei    = (const int*)d_in[1];
    const float* W     = (const float*)d_in[2];
    const float* b     = (const float*)d_in[3];
    const float* gamma = (const float*)d_in[4];
    const float* beta  = (const float*)d_in[5];
    const float* geps  = (const float*)d_in[6];

    const int N = in_sizes[0] / D;
    const int E = in_sizes[1] / 2;
    const int* src = ei;        // edge_index[0,:]
    const int* dst = ei + E;    // edge_index[1,:]

    // ws (~33 MB): [statp][cnt line-padded][xh2][esrc][W16][hlin16]
    char* ws = (char*)d_ws;
    size_t off = 0;
    float* statp = (float*)(ws + off); off += align16((size_t)SC * 256 * 4);
    off = (off + 63) & ~(size_t)63;
    int*   cnt   = (int*)  (ws + off); off += align16((size_t)(N + 1) * CS * 4);
    uint2* xh2   = (uint2*)(ws + off); off += (size_t)N * 32 * 8;
    int*   esrc  = (int*)  (ws + off); off += align16((size_t)N * CAP * 4);
    uint2* W16   = (uint2*)(ws + off); off += (size_t)D * D * 2;
    unsigned short* hlin16 = (unsigned short*)(ws + off); off += (size_t)N * D * 2;

    const int totb = (E + 255) / 256;   // 2500: 1860 scatter + 640 convert
    scatterconv_kernel<<<totb, 256, 0, stream>>>(
        src, dst, cnt, esrc, (const float4*)x, xh2, (const float4*)W, W16,
        statp, E, N);

    const int mtiles = (N + 15) / 16;   // 2500
    gathergemm_kernel<<<mtiles, 256, 0, stream>>>(
        (const uint4*)xh2, cnt, esrc,
        (const unsigned short*)W16, b, geps, hlin16, statp, N);

    long ototal = (long)N * 64;   // uint32 h-pairs / float2 slots
    int oblocks = (int)((ototal + 255) / 256);
    if (oblocks > 2048) oblocks = 2048;
    out_kernel<<<oblocks, 256, 0, stream>>>(
        (const uint32*)hlin16, (const uint32*)xh2, statp, gamma, beta,
        1.0f / (float)N, (float2*)d_out, ototal);
}

// Round 14
// 157.984 us; speedup vs baseline: 1.2635x; 1.2635x over previous
//
#include <hip/hip_runtime.h>
#include <hip/hip_bf16.h>

#define D 128
#define CAP 56  // padded CSR capacity; deg~Poisson(16), P(deg>56) ~ 1e-15/node
#define SC 8    // stats partial copies (contention /8)
#define CS 16   // cnt stride (ints): one counter per 64B line (measured-neutral, kept)
#define NCONVB 640  // convert-specialized blocks (of 2500): convert hides under scatter

typedef unsigned int uint32;
typedef __attribute__((ext_vector_type(8))) short bf16x8;   // 8 bf16 (4 VGPRs)
typedef __attribute__((ext_vector_type(4))) float f32x4;    // MFMA accumulator

__device__ __forceinline__ float bflo(uint32 u) { return __uint_as_float(u << 16); }
__device__ __forceinline__ float bfhi(uint32 u) { return __uint_as_float(u & 0xffff0000u); }
__device__ __forceinline__ unsigned short f2bf(float f) {   // RNE fp32->bf16
    uint32 u = __float_as_uint(f);
    return (unsigned short)((u + 0x7FFFu + ((u >> 16) & 1u)) >> 16);
}

// ---------------------------------------------------------------------------
// scatter+convert, BLOCK-SPECIALIZED (kept from R12; this round measures it
// cleanly): scatter is coherence-point-bound (VALUBusy 2%, BW 18% — R11), so
// 640 of 2500 blocks run the ~31MB conversion concurrently on other CUs,
// hiding its ~5.5us under the scatter's ~38us shadow.
// ---------------------------------------------------------------------------
__global__ __launch_bounds__(256) void scatterconv_kernel(
    const int* __restrict__ src, const int* __restrict__ dst,
    int* __restrict__ cnt, int* __restrict__ esrc,
    const float4* __restrict__ x4, uint2* __restrict__ xh2,
    const float4* __restrict__ W4, uint2* __restrict__ W16,
    float* __restrict__ statp, int E, int N)
{
    const int tid = threadIdx.x;
    const int nb  = gridDim.x;
    const int nsb = nb - NCONVB;            // scatter blocks: [0, nsb)

    if ((int)blockIdx.x < nsb) {
        // ---- scatter specialization ----
        const int gtid  = blockIdx.x * 256 + tid;
        const int gsize = nsb * 256;
        const uint32 sent = (uint32)cnt[(long)N * CS];   // poisoned-uniform

        if (gtid < SC * 256) statp[gtid] = 0.0f;

        for (int e = gtid; e < E; e += gsize) {
            int d = dst[e];
            int s = src[e];                           // issues with dst
            if ((unsigned)d < (unsigned)N) {
                uint32 old = (uint32)atomicAdd(&cnt[(long)d * CS], 1);
                uint32 p = old - sent;                    // 0-based slot
                if (p < (uint32)CAP) {
                    esrc[(long)d * CAP + p] = min(max(s, 0), N - 1);
                }
            }
        }
    } else {
        // ---- convert specialization: x (20.5MB) + W -> bf16 ----
        const int gtid  = (blockIdx.x - nsb) * 256 + tid;
        const int gsize = NCONVB * 256;

        const long total = (long)N * 32;   // float4 slots
        for (long idx = gtid; idx < total; idx += gsize) {
            float4 v = x4[idx];
            uint2 o;
            o.x = (uint32)f2bf(v.x) | ((uint32)f2bf(v.y) << 16);
            o.y = (uint32)f2bf(v.z) | ((uint32)f2bf(v.w) << 16);
            xh2[idx] = o;
        }
        for (int idx = gtid; idx < (D * D) / 4; idx += gsize) {   // 4096 groups
            float4 v = W4[idx];
            uint2 o;
            o.x = (uint32)f2bf(v.x) | ((uint32)f2bf(v.y) << 16);
            o.y = (uint32)f2bf(v.z) | ((uint32)f2bf(v.w) << 16);
            W16[idx] = o;
        }
    }
}

// ---------------------------------------------------------------------------
// Merged gather + MFMA GEMM + BN stats (R7/R11-proven structure).
// R13: REVERTED to __launch_bounds__(256, 4). R12's (256,8) capped VGPR at
// 64 -> compiler chose 32, SPILLED the 2-batch gather pipeline to scratch
// (WRITE_SIZE 12.5 -> 116MB, dur 46 -> 75-84us). The deep-MLP pipeline IS
// the register budget; do not cap below ~56+addr regs. Occupancy 65% at 75us
// vs 34% at 46us also proves occupancy was not the binding constraint.
// NOTE: paste only P##k, never P##k.x — `0.x` lexes as ONE pp-number token.
// ---------------------------------------------------------------------------
#define ROWL(nm, k, jj) \
    uint4 nm; { int j_ = ((k) < deg) ? (jj) : 0; nm = xh4[j_ * 16 + l16]; }

#define BMASK(P, B) \
    if ((B) + 0 >= deg) { (P##0).x = 0u; (P##0).y = 0u; (P##0).z = 0u; (P##0).w = 0u; } \
    if ((B) + 1 >= deg) { (P##1).x = 0u; (P##1).y = 0u; (P##1).z = 0u; (P##1).w = 0u; } \
    if ((B) + 2 >= deg) { (P##2).x = 0u; (P##2).y = 0u; (P##2).z = 0u; (P##2).w = 0u; } \
    if ((B) + 3 >= deg) { (P##3).x = 0u; (P##3).y = 0u; (P##3).z = 0u; (P##3).w = 0u; } \
    if ((B) + 4 >= deg) { (P##4).x = 0u; (P##4).y = 0u; (P##4).z = 0u; (P##4).w = 0u; } \
    if ((B) + 5 >= deg) { (P##5).x = 0u; (P##5).y = 0u; (P##5).z = 0u; (P##5).w = 0u; } \
    if ((B) + 6 >= deg) { (P##6).x = 0u; (P##6).y = 0u; (P##6).z = 0u; (P##6).w = 0u; } \
    if ((B) + 7 >= deg) { (P##7).x = 0u; (P##7).y = 0u; (P##7).z = 0u; (P##7).w = 0u; }

#define ACC8(P) \
    a0 += (bflo((P##0).x)+bflo((P##1).x)) + (bflo((P##2).x)+bflo((P##3).x)) \
        + (bflo((P##4).x)+bflo((P##5).x)) + (bflo((P##6).x)+bflo((P##7).x)); \
    a1 += (bfhi((P##0).x)+bfhi((P##1).x)) + (bfhi((P##2).x)+bfhi((P##3).x)) \
        + (bfhi((P##4).x)+bfhi((P##5).x)) + (bfhi((P##6).x)+bfhi((P##7).x)); \
    a2 += (bflo((P##0).y)+bflo((P##1).y)) + (bflo((P##2).y)+bflo((P##3).y)) \
        + (bflo((P##4).y)+bflo((P##5).y)) + (bflo((P##6).y)+bflo((P##7).y)); \
    a3 += (bfhi((P##0).y)+bfhi((P##1).y)) + (bfhi((P##2).y)+bfhi((P##3).y)) \
        + (bfhi((P##4).y)+bfhi((P##5).y)) + (bfhi((P##6).y)+bfhi((P##7).y)); \
    a4 += (bflo((P##0).z)+bflo((P##1).z)) + (bflo((P##2).z)+bflo((P##3).z)) \
        + (bflo((P##4).z)+bflo((P##5).z)) + (bflo((P##6).z)+bflo((P##7).z)); \
    a5 += (bfhi((P##0).z)+bfhi((P##1).z)) + (bfhi((P##2).z)+bfhi((P##3).z)) \
        + (bfhi((P##4).z)+bfhi((P##5).z)) + (bfhi((P##6).z)+bfhi((P##7).z)); \
    a6 += (bflo((P##0).w)+bflo((P##1).w)) + (bflo((P##2).w)+bflo((P##3).w)) \
        + (bflo((P##4).w)+bflo((P##5).w)) + (bflo((P##6).w)+bflo((P##7).w)); \
    a7 += (bfhi((P##0).w)+bfhi((P##1).w)) + (bfhi((P##2).w)+bfhi((P##3).w)) \
        + (bfhi((P##4).w)+bfhi((P##5).w)) + (bfhi((P##6).w)+bfhi((P##7).w));

__global__ __launch_bounds__(256, 4) void gathergemm_kernel(
    const uint4* __restrict__ xh4,
    const int* __restrict__ cnt, const int* __restrict__ esrc,
    const unsigned short* __restrict__ W16, const float* __restrict__ bb,
    const float* __restrict__ geps, unsigned short* __restrict__ hlin16,
    float* __restrict__ statp, int N)
{
    __shared__ __align__(16) unsigned short hl[16][136];
    __shared__ float bias_s[D];

    const int tid = threadIdx.x;
    if (tid < D) bias_s[tid] = bb[tid];
    const float eps1 = 1.0f + geps[0];
    const uint32 sent = (uint32)cnt[(long)N * CS];
    const int row0 = blockIdx.x * 16;

    // ---- phase 1: gather 16 rows into LDS (one 16-lane group per row) ----
    const int grp = tid >> 4;     // 0..15 -> row
    const int l16 = tid & 15;     // uint4 slot (16B of the 256B bf16 row)
    {
        const int node = row0 + grp;
        float a0=0.f,a1=0.f,a2=0.f,a3=0.f,a4=0.f,a5=0.f,a6=0.f,a7=0.f;
        int deg = 0; long base = 0;
        int4 ja0 = {0,0,0,0}, jb0 = {0,0,0,0}, ja1 = {0,0,0,0}, jb1 = {0,0,0,0},
             ja2 = {0,0,0,0}, jb2 = {0,0,0,0}, ja3 = {0,0,0,0}, jb3 = {0,0,0,0};
        if (node < N) {
            // everything below issues concurrently: cnt, 32 indices, self row
            deg  = min((int)((uint32)cnt[(long)node * CS] - sent), CAP);
            base = (long)node * CAP;
            const int4* jp = (const int4*)(esrc + base);   // 16B-aligned (224B rows)
            ja0 = jp[0]; jb0 = jp[1]; ja1 = jp[2]; jb1 = jp[3];
            ja2 = jp[4]; jb2 = jp[5]; ja3 = jp[6]; jb3 = jp[7];
            uint4 sx = xh4[(long)node * 16 + l16];         // self row (bf16)
            a0 = bflo(sx.x) * eps1; a1 = bfhi(sx.x) * eps1;
            a2 = bflo(sx.y) * eps1; a3 = bfhi(sx.y) * eps1;
            a4 = bflo(sx.z) * eps1; a5 = bfhi(sx.z) * eps1;
            a6 = bflo(sx.w) * eps1; a7 = bfhi(sx.w) * eps1;
        }
        // B0 + B1 in flight
        ROWL(u00,  0, ja0.x) ROWL(u01,  1, ja0.y) ROWL(u02,  2, ja0.z) ROWL(u03,  3, ja0.w)
        ROWL(u04,  4, jb0.x) ROWL(u05,  5, jb0.y) ROWL(u06,  6, jb0.z) ROWL(u07,  7, jb0.w)
        ROWL(u10,  8, ja1.x) ROWL(u11,  9, ja1.y) ROWL(u12, 10, ja1.z) ROWL(u13, 11, ja1.w)
        ROWL(u14, 12, jb1.x) ROWL(u15, 13, jb1.y) ROWL(u16, 14, jb1.z) ROWL(u17, 15, jb1.w)
        // acc B0 | issue B2
        ROWL(u20, 16, ja2.x) ROWL(u21, 17, ja2.y) ROWL(u22, 18, ja2.z) ROWL(u23, 19, ja2.w)
        ROWL(u24, 20, jb2.x) ROWL(u25, 21, jb2.y) ROWL(u26, 22, jb2.z) ROWL(u27, 23, jb2.w)
        BMASK(u0, 0)
        ACC8(u0)
        // acc B1 | issue B3
        ROWL(u30, 24, ja3.x) ROWL(u31, 25, ja3.y) ROWL(u32, 26, ja3.z) ROWL(u33, 27, ja3.w)
        ROWL(u34, 28, jb3.x) ROWL(u35, 29, jb3.y) ROWL(u36, 30, jb3.z) ROWL(u37, 31, jb3.w)
        BMASK(u1, 8)
        ACC8(u1)
        BMASK(u2, 16)
        ACC8(u2)
        BMASK(u3, 24)
        ACC8(u3)
        // rare tail (P(deg>32) ~ 1e-4)
        for (int e = 32; e < deg; ++e) {
            int j = esrc[base + e];
            uint4 u = xh4[j * 16 + l16];
            a0 += bflo(u.x); a1 += bfhi(u.x);
            a2 += bflo(u.y); a3 += bfhi(u.y);
            a4 += bflo(u.z); a5 += bfhi(u.z);
            a6 += bflo(u.w); a7 += bfhi(u.w);
        }
        uint4 o;
        o.x = (uint32)f2bf(a0) | ((uint32)f2bf(a1) << 16);
        o.y = (uint32)f2bf(a2) | ((uint32)f2bf(a3) << 16);
        o.z = (uint32)f2bf(a4) | ((uint32)f2bf(a5) << 16);
        o.w = (uint32)f2bf(a6) | ((uint32)f2bf(a7) << 16);
        *(uint4*)&hl[grp][l16 * 8] = o;
    }
    __syncthreads();

    // ---- phase 2: MFMA (wave w -> N-tiles 2w, 2w+1) ----
    const int wave = tid >> 6;
    const int l64  = tid & 63;
    const int m    = l64 & 15;
    const int quad = l64 >> 4;

    f32x4 acc0 = (f32x4){0.f, 0.f, 0.f, 0.f};
    f32x4 acc1 = (f32x4){0.f, 0.f, 0.f, 0.f};
    const int n0 = (2 * wave) * 16 + m;
    const int n1 = n0 + 16;
    #pragma unroll
    for (int ks = 0; ks < 4; ++ks) {
        bf16x8 afrag = *(const bf16x8*)&hl[m][ks * 32 + quad * 8];
        bf16x8 b0 = *(const bf16x8*)(W16 + ((long)n0 * D + ks * 32 + quad * 8));
        bf16x8 b1 = *(const bf16x8*)(W16 + ((long)n1 * D + ks * 32 + quad * 8));
        acc0 = __builtin_amdgcn_mfma_f32_16x16x32_bf16(afrag, b0, acc0, 0, 0, 0);
        acc1 = __builtin_amdgcn_mfma_f32_16x16x32_bf16(afrag, b1, acc1, 0, 0, 0);
    }

    // epilogue: bias, bf16 hlin store (stats from fp32), split atomics
    float* sp = statp + (blockIdx.x & (SC - 1)) * 256;
    #pragma unroll
    for (int t = 0; t < 2; ++t) {
        const int col = t ? n1 : n0;              // (2w+t)*16 + m
        const float bias = bias_s[col];
        float ps = 0.f, pq = 0.f;
        #pragma unroll
        for (int r = 0; r < 4; ++r) {
            int gr = row0 + quad * 4 + r;
            float v = (t ? acc1[r] : acc0[r]) + bias;
            if (gr < N) {
                hlin16[(long)gr * D + col] = f2bf(v);
                ps += v;
                pq = fmaf(v, v, pq);
            }
        }
        ps += __shfl_xor(ps, 16); ps += __shfl_xor(ps, 32);
        pq += __shfl_xor(pq, 16); pq += __shfl_xor(pq, 32);
        if (quad == 0) {
            unsafeAtomicAdd(&sp[col],       ps);
            unsafeAtomicAdd(&sp[128 + col], pq);
        }
    }
}

// ---------------------------------------------------------------------------
// Epilogue: sum the SC stats partials -> mean/var -> out = relu(..)+x.
// Reads bf16 h AND bf16 x (both uint32 = 2 cols; same indexing) — residual
// from bf16 x adds <=0.004 abs error (headroom 0.12). Writes fp32 out.
// Grid-stride at 2048 blocks (stats recompute amortized).
// ---------------------------------------------------------------------------
__global__ __launch_bounds__(256) void out_kernel(
    const uint32* __restrict__ h32, const uint32* __restrict__ xh32,
    const float* __restrict__ statp, const float* __restrict__ gamma,
    const float* __restrict__ beta, float invN, float2* __restrict__ dout,
    long total)
{
    __shared__ float ginv[D], sh[D];
    if (threadIdx.x < D) {
        int j = threadIdx.x;
        float s = 0.f, q = 0.f;
        #pragma unroll
        for (int cp = 0; cp < SC; ++cp) {
            s += statp[cp * 256 + j];
            q += statp[cp * 256 + 128 + j];
        }
        float mean = s * invN;
        float var  = q * invN - mean * mean;
        float gv   = gamma[j] * rsqrtf(var + 1e-5f);
        ginv[j] = gv;
        sh[j]   = beta[j] - mean * gv;
    }
    __syncthreads();
    const long stride = (long)gridDim.x * 256;
    for (long t = (long)blockIdx.x * 256 + threadIdx.x; t < total; t += stride) {
        int f = (int)(t & 63);
        uint32 hv = h32[t];
        uint32 xv = xh32[t];
        float v0 = fmaf(bflo(hv), ginv[2 * f],     sh[2 * f]);
        float v1 = fmaf(bfhi(hv), ginv[2 * f + 1], sh[2 * f + 1]);
        v0 = fmaxf(v0, 0.0f) + bflo(xv);
        v1 = fmaxf(v1, 0.0f) + bfhi(xv);
        dout[t] = make_float2(v0, v1);
    }
}

// ---------------------------------------------------------------------------
static inline size_t align16(size_t v) { return (v + 15) & ~(size_t)15; }

extern "C" void kernel_launch(void* const* d_in, const int* in_sizes, int n_in,
                              void* d_out, int out_size, void* d_ws, size_t ws_size,
                              hipStream_t stream)
{
    const float* x     = (const float*)d_in[0];
    const int*   ei    = (const int*)d_in[1];
    const float* W     = (const float*)d_in[2];
    const float* b     = (const float*)d_in[3];
    const float* gamma = (const float*)d_in[4];
    const float* beta  = (const float*)d_in[5];
    const float* geps  = (const float*)d_in[6];

    const int N = in_sizes[0] / D;
    const int E = in_sizes[1] / 2;
    const int* src = ei;        // edge_index[0,:]
    const int* dst = ei + E;    // edge_index[1,:]

    // ws (~33 MB): [statp][cnt line-padded][xh2][esrc][W16][hlin16]
    char* ws = (char*)d_ws;
    size_t off = 0;
    float* statp = (float*)(ws + off); off += align16((size_t)SC * 256 * 4);
    off = (off + 63) & ~(size_t)63;
    int*   cnt   = (int*)  (ws + off); off += align16((size_t)(N + 1) * CS * 4);
    uint2* xh2   = (uint2*)(ws + off); off += (size_t)N * 32 * 8;
    int*   esrc  = (int*)  (ws + off); off += align16((size_t)N * CAP * 4);
    uint2* W16   = (uint2*)(ws + off); off += (size_t)D * D * 2;
    unsigned short* hlin16 = (unsigned short*)(ws + off); off += (size_t)N * D * 2;

    const int totb = (E + 255) / 256;   // 2500: 1860 scatter + 640 convert
    scatterconv_kernel<<<totb, 256, 0, stream>>>(
        src, dst, cnt, esrc, (const float4*)x, xh2, (const float4*)W, W16,
        statp, E, N);

    const int mtiles = (N + 15) / 16;   // 2500
    gathergemm_kernel<<<mtiles, 256, 0, stream>>>(
        (const uint4*)xh2, cnt, esrc,
        (const unsigned short*)W16, b, geps, hlin16, statp, N);

    long ototal = (long)N * 64;   // uint32 h-pairs / float2 slots
    int oblocks = (int)((ototal + 255) / 256);
    if (oblocks > 2048) oblocks = 2048;
    out_kernel<<<oblocks, 256, 0, stream>>>(
        (const uint32*)hlin16, (const uint32*)xh2, statp, gamma, beta,
        1.0f / (float)N, (float2*)d_out, ototal);
}

// Round 19
// 153.447 us; speedup vs baseline: 1.3009x; 1.0296x over previous
//
#include <hip/hip_runtime.h>
#include <hip/hip_bf16.h>

#define D 128
#define CAP 56  // padded CSR capacity; deg~Poisson(16), P(deg>56) ~ 1e-15/node
#define SC 8    // stats partial copies (contention /8)
#define CS 16   // cnt stride (ints): one counter per 64B line (measured-neutral, kept)

typedef unsigned int uint32;
typedef __attribute__((ext_vector_type(8))) short bf16x8;   // 8 bf16 (4 VGPRs)
typedef __attribute__((ext_vector_type(4))) float f32x4;    // MFMA accumulator

__device__ __forceinline__ float bflo(uint32 u) { return __uint_as_float(u << 16); }
__device__ __forceinline__ float bfhi(uint32 u) { return __uint_as_float(u & 0xffff0000u); }
__device__ __forceinline__ unsigned short f2bf(float f) {   // RNE fp32->bf16
    uint32 u = __float_as_uint(f);
    return (unsigned short)((u + 0x7FFFu + ((u >> 16) & 1u)) >> 16);
}

// ---------------------------------------------------------------------------
// fill+compress, COMBINED (R14 = revert to R10's measured-best 43.6us):
// 2500 blocks, ONE edge per thread (R13 proved 1860 blocks -> 1.34 serial
// edges/thread costs +5us; the serial per-thread chain sets duration).
// Atomic issued up front; conversion runs in its shadow; dependent esrc
// store last. cnt line-padded; sentinel = poisoned cnt[N*CS].
// ---------------------------------------------------------------------------
__global__ __launch_bounds__(256) void fillcompress_kernel(
    const int* __restrict__ src, const int* __restrict__ dst,
    int* __restrict__ cnt, int* __restrict__ esrc,
    const float4* __restrict__ x4, uint2* __restrict__ xh2,
    const float4* __restrict__ W4, uint2* __restrict__ W16,
    float* __restrict__ statp, int E, int N)
{
    const int gtid  = blockIdx.x * 256 + threadIdx.x;
    const int gsize = gridDim.x * 256;
    const uint32 sent = (uint32)cnt[(long)N * CS];   // never modified -> stable

    if (gtid < SC * 256) statp[gtid] = 0.0f;

    // ---- scatter, part 1: loads + atomic issued up front ----
    int d = 0, s = 0; uint32 old = 0; bool act = false;
    if (gtid < E) {
        d = dst[gtid];
        s = src[gtid];
        if ((unsigned)d < (unsigned)N) {
            old = (uint32)atomicAdd(&cnt[(long)d * CS], 1);
            act = true;
        }
    }

    // ---- conversion work overlaps the atomic's return latency ----
    const long total = (long)N * 32;   // float4 slots
    for (long idx = gtid; idx < total; idx += gsize) {
        float4 v = x4[idx];
        uint2 o;
        o.x = (uint32)f2bf(v.x) | ((uint32)f2bf(v.y) << 16);
        o.y = (uint32)f2bf(v.z) | ((uint32)f2bf(v.w) << 16);
        xh2[idx] = o;
    }
    for (int idx = gtid; idx < (D * D) / 4; idx += gsize) {   // 4096 groups
        float4 v = W4[idx];
        uint2 o;
        o.x = (uint32)f2bf(v.x) | ((uint32)f2bf(v.y) << 16);
        o.y = (uint32)f2bf(v.z) | ((uint32)f2bf(v.w) << 16);
        W16[idx] = o;
    }

    // ---- scatter, part 2: dependent store ----
    if (act) {
        uint32 p = old - sent;                    // 0-based slot
        if (p < (uint32)CAP) {
            esrc[(long)d * CAP + p] = min(max(s, 0), N - 1);
        }
    }
    // tail (not reached at E <= gsize; kept for generality)
    for (int e = gtid + gsize; e < E; e += gsize) {
        int dd = dst[e];
        int ss = src[e];
        if ((unsigned)dd < (unsigned)N) {
            uint32 o2 = (uint32)atomicAdd(&cnt[(long)dd * CS], 1);
            uint32 p = o2 - sent;
            if (p < (uint32)CAP) {
                esrc[(long)dd * CAP + p] = min(max(ss, 0), N - 1);
            }
        }
    }
}

// ---------------------------------------------------------------------------
// Merged gather + MFMA GEMM + BN stats (R7/R11-proven structure).
// __launch_bounds__(256, 4): R12's (256,8) capped VGPR at 64 -> 32, spilled
// the 2-batch gather pipeline (WRITE 12.5->116MB, dur 46->75+). The deep-MLP
// pipeline IS the register budget; occupancy was not binding (65%@75us vs
// 34%@46us). Do not cap below the ~56-VGPR signature.
// NOTE: paste only P##k, never P##k.x — `0.x` lexes as ONE pp-number token.
// ---------------------------------------------------------------------------
#define ROWL(nm, k, jj) \
    uint4 nm; { int j_ = ((k) < deg) ? (jj) : 0; nm = xh4[j_ * 16 + l16]; }

#define BMASK(P, B) \
    if ((B) + 0 >= deg) { (P##0).x = 0u; (P##0).y = 0u; (P##0).z = 0u; (P##0).w = 0u; } \
    if ((B) + 1 >= deg) { (P##1).x = 0u; (P##1).y = 0u; (P##1).z = 0u; (P##1).w = 0u; } \
    if ((B) + 2 >= deg) { (P##2).x = 0u; (P##2).y = 0u; (P##2).z = 0u; (P##2).w = 0u; } \
    if ((B) + 3 >= deg) { (P##3).x = 0u; (P##3).y = 0u; (P##3).z = 0u; (P##3).w = 0u; } \
    if ((B) + 4 >= deg) { (P##4).x = 0u; (P##4).y = 0u; (P##4).z = 0u; (P##4).w = 0u; } \
    if ((B) + 5 >= deg) { (P##5).x = 0u; (P##5).y = 0u; (P##5).z = 0u; (P##5).w = 0u; } \
    if ((B) + 6 >= deg) { (P##6).x = 0u; (P##6).y = 0u; (P##6).z = 0u; (P##6).w = 0u; } \
    if ((B) + 7 >= deg) { (P##7).x = 0u; (P##7).y = 0u; (P##7).z = 0u; (P##7).w = 0u; }

#define ACC8(P) \
    a0 += (bflo((P##0).x)+bflo((P##1).x)) + (bflo((P##2).x)+bflo((P##3).x)) \
        + (bflo((P##4).x)+bflo((P##5).x)) + (bflo((P##6).x)+bflo((P##7).x)); \
    a1 += (bfhi((P##0).x)+bfhi((P##1).x)) + (bfhi((P##2).x)+bfhi((P##3).x)) \
        + (bfhi((P##4).x)+bfhi((P##5).x)) + (bfhi((P##6).x)+bfhi((P##7).x)); \
    a2 += (bflo((P##0).y)+bflo((P##1).y)) + (bflo((P##2).y)+bflo((P##3).y)) \
        + (bflo((P##4).y)+bflo((P##5).y)) + (bflo((P##6).y)+bflo((P##7).y)); \
    a3 += (bfhi((P##0).y)+bfhi((P##1).y)) + (bfhi((P##2).y)+bfhi((P##3).y)) \
        + (bfhi((P##4).y)+bfhi((P##5).y)) + (bfhi((P##6).y)+bfhi((P##7).y)); \
    a4 += (bflo((P##0).z)+bflo((P##1).z)) + (bflo((P##2).z)+bflo((P##3).z)) \
        + (bflo((P##4).z)+bflo((P##5).z)) + (bflo((P##6).z)+bflo((P##7).z)); \
    a5 += (bfhi((P##0).z)+bfhi((P##1).z)) + (bfhi((P##2).z)+bfhi((P##3).z)) \
        + (bfhi((P##4).z)+bfhi((P##5).z)) + (bfhi((P##6).z)+bfhi((P##7).z)); \
    a6 += (bflo((P##0).w)+bflo((P##1).w)) + (bflo((P##2).w)+bflo((P##3).w)) \
        + (bflo((P##4).w)+bflo((P##5).w)) + (bflo((P##6).w)+bflo((P##7).w)); \
    a7 += (bfhi((P##0).w)+bfhi((P##1).w)) + (bfhi((P##2).w)+bfhi((P##3).w)) \
        + (bfhi((P##4).w)+bfhi((P##5).w)) + (bfhi((P##6).w)+bfhi((P##7).w));

__global__ __launch_bounds__(256, 4) void gathergemm_kernel(
    const uint4* __restrict__ xh4,
    const int* __restrict__ cnt, const int* __restrict__ esrc,
    const unsigned short* __restrict__ W16, const float* __restrict__ bb,
    const float* __restrict__ geps, unsigned short* __restrict__ hlin16,
    float* __restrict__ statp, int N)
{
    __shared__ __align__(16) unsigned short hl[16][136];
    __shared__ float bias_s[D];

    const int tid = threadIdx.x;
    if (tid < D) bias_s[tid] = bb[tid];
    const float eps1 = 1.0f + geps[0];
    const uint32 sent = (uint32)cnt[(long)N * CS];
    const int row0 = blockIdx.x * 16;

    // ---- phase 1: gather 16 rows into LDS (one 16-lane group per row) ----
    const int grp = tid >> 4;     // 0..15 -> row
    const int l16 = tid & 15;     // uint4 slot (16B of the 256B bf16 row)
    {
        const int node = row0 + grp;
        float a0=0.f,a1=0.f,a2=0.f,a3=0.f,a4=0.f,a5=0.f,a6=0.f,a7=0.f;
        int deg = 0; long base = 0;
        int4 ja0 = {0,0,0,0}, jb0 = {0,0,0,0}, ja1 = {0,0,0,0}, jb1 = {0,0,0,0},
             ja2 = {0,0,0,0}, jb2 = {0,0,0,0}, ja3 = {0,0,0,0}, jb3 = {0,0,0,0};
        if (node < N) {
            // everything below issues concurrently: cnt, 32 indices, self row
            deg  = min((int)((uint32)cnt[(long)node * CS] - sent), CAP);
            base = (long)node * CAP;
            const int4* jp = (const int4*)(esrc + base);   // 16B-aligned (224B rows)
            ja0 = jp[0]; jb0 = jp[1]; ja1 = jp[2]; jb1 = jp[3];
            ja2 = jp[4]; jb2 = jp[5]; ja3 = jp[6]; jb3 = jp[7];
            uint4 sx = xh4[(long)node * 16 + l16];         // self row (bf16)
            a0 = bflo(sx.x) * eps1; a1 = bfhi(sx.x) * eps1;
            a2 = bflo(sx.y) * eps1; a3 = bfhi(sx.y) * eps1;
            a4 = bflo(sx.z) * eps1; a5 = bfhi(sx.z) * eps1;
            a6 = bflo(sx.w) * eps1; a7 = bfhi(sx.w) * eps1;
        }
        // B0 + B1 in flight
        ROWL(u00,  0, ja0.x) ROWL(u01,  1, ja0.y) ROWL(u02,  2, ja0.z) ROWL(u03,  3, ja0.w)
        ROWL(u04,  4, jb0.x) ROWL(u05,  5, jb0.y) ROWL(u06,  6, jb0.z) ROWL(u07,  7, jb0.w)
        ROWL(u10,  8, ja1.x) ROWL(u11,  9, ja1.y) ROWL(u12, 10, ja1.z) ROWL(u13, 11, ja1.w)
        ROWL(u14, 12, jb1.x) ROWL(u15, 13, jb1.y) ROWL(u16, 14, jb1.z) ROWL(u17, 15, jb1.w)
        // acc B0 | issue B2
        ROWL(u20, 16, ja2.x) ROWL(u21, 17, ja2.y) ROWL(u22, 18, ja2.z) ROWL(u23, 19, ja2.w)
        ROWL(u24, 20, jb2.x) ROWL(u25, 21, jb2.y) ROWL(u26, 22, jb2.z) ROWL(u27, 23, jb2.w)
        BMASK(u0, 0)
        ACC8(u0)
        // acc B1 | issue B3
        ROWL(u30, 24, ja3.x) ROWL(u31, 25, ja3.y) ROWL(u32, 26, ja3.z) ROWL(u33, 27, ja3.w)
        ROWL(u34, 28, jb3.x) ROWL(u35, 29, jb3.y) ROWL(u36, 30, jb3.z) ROWL(u37, 31, jb3.w)
        BMASK(u1, 8)
        ACC8(u1)
        BMASK(u2, 16)
        ACC8(u2)
        BMASK(u3, 24)
        ACC8(u3)
        // rare tail (P(deg>32) ~ 1e-4)
        for (int e = 32; e < deg; ++e) {
            int j = esrc[base + e];
            uint4 u = xh4[j * 16 + l16];
            a0 += bflo(u.x); a1 += bfhi(u.x);
            a2 += bflo(u.y); a3 += bfhi(u.y);
            a4 += bflo(u.z); a5 += bfhi(u.z);
            a6 += bflo(u.w); a7 += bfhi(u.w);
        }
        uint4 o;
        o.x = (uint32)f2bf(a0) | ((uint32)f2bf(a1) << 16);
        o.y = (uint32)f2bf(a2) | ((uint32)f2bf(a3) << 16);
        o.z = (uint32)f2bf(a4) | ((uint32)f2bf(a5) << 16);
        o.w = (uint32)f2bf(a6) | ((uint32)f2bf(a7) << 16);
        *(uint4*)&hl[grp][l16 * 8] = o;
    }
    __syncthreads();

    // ---- phase 2: MFMA (wave w -> N-tiles 2w, 2w+1) ----
    const int wave = tid >> 6;
    const int l64  = tid & 63;
    const int m    = l64 & 15;
    const int quad = l64 >> 4;

    f32x4 acc0 = (f32x4){0.f, 0.f, 0.f, 0.f};
    f32x4 acc1 = (f32x4){0.f, 0.f, 0.f, 0.f};
    const int n0 = (2 * wave) * 16 + m;
    const int n1 = n0 + 16;
    #pragma unroll
    for (int ks = 0; ks < 4; ++ks) {
        bf16x8 afrag = *(const bf16x8*)&hl[m][ks * 32 + quad * 8];
        bf16x8 b0 = *(const bf16x8*)(W16 + ((long)n0 * D + ks * 32 + quad * 8));
        bf16x8 b1 = *(const bf16x8*)(W16 + ((long)n1 * D + ks * 32 + quad * 8));
        acc0 = __builtin_amdgcn_mfma_f32_16x16x32_bf16(afrag, b0, acc0, 0, 0, 0);
        acc1 = __builtin_amdgcn_mfma_f32_16x16x32_bf16(afrag, b1, acc1, 0, 0, 0);
    }

    // epilogue: bias, bf16 hlin store (stats from fp32), split atomics
    float* sp = statp + (blockIdx.x & (SC - 1)) * 256;
    #pragma unroll
    for (int t = 0; t < 2; ++t) {
        const int col = t ? n1 : n0;              // (2w+t)*16 + m
        const float bias = bias_s[col];
        float ps = 0.f, pq = 0.f;
        #pragma unroll
        for (int r = 0; r < 4; ++r) {
            int gr = row0 + quad * 4 + r;
            float v = (t ? acc1[r] : acc0[r]) + bias;
            if (gr < N) {
                hlin16[(long)gr * D + col] = f2bf(v);
                ps += v;
                pq = fmaf(v, v, pq);
            }
        }
        ps += __shfl_xor(ps, 16); ps += __shfl_xor(ps, 32);
        pq += __shfl_xor(pq, 16); pq += __shfl_xor(pq, 32);
        if (quad == 0) {
            unsafeAtomicAdd(&sp[col],       ps);
            unsafeAtomicAdd(&sp[128 + col], pq);
        }
    }
}

// ---------------------------------------------------------------------------
// Epilogue: sum the SC stats partials -> mean/var -> out = relu(..)+x.
// Reads bf16 h AND bf16 x (both uint32 = 2 cols; same indexing) — residual
// from bf16 x adds <=0.004 abs error (headroom 0.12). Writes fp32 out.
// Grid-stride at 2048 blocks (stats recompute amortized).
// ---------------------------------------------------------------------------
__global__ __launch_bounds__(256) void out_kernel(
    const uint32* __restrict__ h32, const uint32* __restrict__ xh32,
    const float* __restrict__ statp, const float* __restrict__ gamma,
    const float* __restrict__ beta, float invN, float2* __restrict__ dout,
    long total)
{
    __shared__ float ginv[D], sh[D];
    if (threadIdx.x < D) {
        int j = threadIdx.x;
        float s = 0.f, q = 0.f;
        #pragma unroll
        for (int cp = 0; cp < SC; ++cp) {
            s += statp[cp * 256 + j];
            q += statp[cp * 256 + 128 + j];
        }
        float mean = s * invN;
        float var  = q * invN - mean * mean;
        float gv   = gamma[j] * rsqrtf(var + 1e-5f);
        ginv[j] = gv;
        sh[j]   = beta[j] - mean * gv;
    }
    __syncthreads();
    const long stride = (long)gridDim.x * 256;
    for (long t = (long)blockIdx.x * 256 + threadIdx.x; t < total; t += stride) {
        int f = (int)(t & 63);
        uint32 hv = h32[t];
        uint32 xv = xh32[t];
        float v0 = fmaf(bflo(hv), ginv[2 * f],     sh[2 * f]);
        float v1 = fmaf(bfhi(hv), ginv[2 * f + 1], sh[2 * f + 1]);
        v0 = fmaxf(v0, 0.0f) + bflo(xv);
        v1 = fmaxf(v1, 0.0f) + bfhi(xv);
        dout[t] = make_float2(v0, v1);
    }
}

// ---------------------------------------------------------------------------
static inline size_t align16(size_t v) { return (v + 15) & ~(size_t)15; }

extern "C" void kernel_launch(void* const* d_in, const int* in_sizes, int n_in,
                              void* d_out, int out_size, void* d_ws, size_t ws_size,
                              hipStream_t stream)
{
    const float* x     = (const float*)d_in[0];
    const int*   ei    = (const int*)d_in[1];
    const float* W     = (const float*)d_in[2];
    const float* b     = (const float*)d_in[3];
    const float* gamma = (const float*)d_in[4];
    const float* beta  = (const float*)d_in[5];
    const float* geps  = (const float*)d_in[6];

    const int N = in_sizes[0] / D;
    const int E = in_sizes[1] / 2;
    const int* src = ei;        // edge_index[0,:]
    const int* dst = ei + E;    // edge_index[1,:]

    // ws (~33 MB): [statp][cnt line-padded][xh2][esrc][W16][hlin16]
    char* ws = (char*)d_ws;
    size_t off = 0;
    float* statp = (float*)(ws + off); off += align16((size_t)SC * 256 * 4);
    off = (off + 63) & ~(size_t)63;
    int*   cnt   = (int*)  (ws + off); off += align16((size_t)(N + 1) * CS * 4);
    uint2* xh2   = (uint2*)(ws + off); off += (size_t)N * 32 * 8;
    int*   esrc  = (int*)  (ws + off); off += align16((size_t)N * CAP * 4);
    uint2* W16   = (uint2*)(ws + off); off += (size_t)D * D * 2;
    unsigned short* hlin16 = (unsigned short*)(ws + off); off += (size_t)N * D * 2;

    fillcompress_kernel<<<(E + 255) / 256, 256, 0, stream>>>(
        src, dst, cnt, esrc, (const float4*)x, xh2, (const float4*)W, W16,
        statp, E, N);

    const int mtiles = (N + 15) / 16;   // 2500
    gathergemm_kernel<<<mtiles, 256, 0, stream>>>(
        (const uint4*)xh2, cnt, esrc,
        (const unsigned short*)W16, b, geps, hlin16, statp, N);

    long ototal = (long)N * 64;   // uint32 h-pairs / float2 slots
    int oblocks = (int)((ototal + 255) / 256);
    if (oblocks > 2048) oblocks = 2048;
    out_kernel<<<oblocks, 256, 0, stream>>>(
        (const uint32*)hlin16, (const uint32*)xh2, statp, gamma, beta,
        1.0f / (float)N, (float2*)d_out, ototal);
}